// Round 6
// baseline (2896.714 us; speedup 1.0000x reference)
//
#include <hip/hip_runtime.h>
#include <stdint.h>

#define T_STEPS 512
#define BATCH   64
#define DIM     512            // D == H == 512
#define NGROUP  8              // one group per XCD (blockIdx % 8 under round-robin)
#define WG_PER_GROUP 32
#define GB      8              // batch rows per group (B = 64 = 8 groups x 8 rows)
#define TBH     (T_STEPS*BATCH*DIM)
#define BH      (BATCH*DIM)
#define TAGM    0x00010001u

typedef __attribute__((ext_vector_type(8))) short short8;
typedef __attribute__((ext_vector_type(4))) float f32x4;
typedef __attribute__((ext_vector_type(4))) unsigned int u32x4;
typedef unsigned short u16;

__device__ __forceinline__ u16 f2bf(float f) {
  union { float f; uint32_t u; } c; c.f = f;
  uint32_t u = c.u;
  return (u16)((u + 0x7FFFu + ((u >> 16) & 1u)) >> 16);
}

__device__ __forceinline__ float fsigmoid(float x) {
  float e = __expf(-x);
  return __builtin_amdgcn_rcpf(1.f + e);
}
__device__ __forceinline__ float ftanh(float x) {
  float e = __expf(2.f * x);
  return 1.f - 2.f * __builtin_amdgcn_rcpf(e + 1.f);
}

// ---- pack w_ih|w_hh into per-colslice bf16 MFMA B-fragment images -----------
// image j (j=0..31): unit u = (gate w 0..3, ktile kt 0..31, lane 0..63), 8 bf16:
//   n = w*512 + j*16 + (lane&15);  k = kt*32 + 8*(lane>>4) + 0..7
//   k<512 -> w_ih[n][k], else w_hh[n][k-512]
__global__ void pack_w_kernel(const float* __restrict__ w_ih,
                              const float* __restrict__ w_hh,
                              uint4* __restrict__ wpack) {
  int j = blockIdx.x;
  for (int u = threadIdx.x; u < 8192; u += 256) {
    int w    = u >> 11;
    int kt   = (u >> 6) & 31;
    int lane = u & 63;
    int n  = w * 512 + j * 16 + (lane & 15);
    int k0 = kt * 32 + 8 * (lane >> 4);
    const float* src = (k0 < 512) ? (w_ih + (size_t)n * 512 + k0)
                                  : (w_hh + (size_t)n * 512 + (k0 - 512));
    uint32_t p0 = f2bf(src[0]) | ((uint32_t)f2bf(src[1]) << 16);
    uint32_t p1 = f2bf(src[2]) | ((uint32_t)f2bf(src[3]) << 16);
    uint32_t p2 = f2bf(src[4]) | ((uint32_t)f2bf(src[5]) << 16);
    uint32_t p3 = f2bf(src[6]) | ((uint32_t)f2bf(src[7]) << 16);
    wpack[(size_t)j * 8192 + u] = make_uint4(p0, p1, p2, p3);
  }
}

// ---- x (fp32) -> bf16, same [T][B][D] layout --------------------------------
__global__ void pack_x_kernel(const float* __restrict__ x, uint4* __restrict__ xbf) {
  size_t i = (size_t)blockIdx.x * 256 + threadIdx.x;     // unit of 8 elems
  const float4* src = (const float4*)x + i * 2;
  float4 a = src[0], b = src[1];
  uint32_t p0 = f2bf(a.x) | ((uint32_t)f2bf(a.y) << 16);
  uint32_t p1 = f2bf(a.z) | ((uint32_t)f2bf(a.w) << 16);
  uint32_t p2 = f2bf(b.x) | ((uint32_t)f2bf(b.y) << 16);
  uint32_t p3 = f2bf(b.z) | ((uint32_t)f2bf(b.w) << 16);
  xbf[i] = make_uint4(p0, p1, p2, p3);
}

// ---- persistent LSTM --------------------------------------------------------
// Exchange: every bf16 of the h-tile carries a generation tag in its LSB.
// Producer: write-through stores (sc0 sc1 -> LLC + own-L2 consistent).
// Consumer: retry-load full tile with sc0-ONLY (L2-served; fast when the whole
// group shares one XCD). Stale L2 hits fail the tag check; after `esc` failed
// retries the wave escalates PERMANENTLY to sc0+sc1 (known-correct far path).
// A tag-match on 2-stale data is unreachable: the 1-stale mismatch one
// generation earlier forces sticky first.
// Tags: write at step t uses tag_w = 1^(((t+1)>>1)&1) (h0: tag 1);
// reader at step t expects e = 1^((t>>1)&1). Poison (0xAA -> LSB 0) only ever
// meets expected-tag-1 reads (t=0,1) -> no false validation.
__launch_bounds__(256, 1)
__global__ void lstm_persist(const float* __restrict__ h0, const float* __restrict__ c0,
                             const float* __restrict__ b_ih, const float* __restrict__ b_hh,
                             const uint4* __restrict__ wpack, const u16* __restrict__ xbf,
                             u16* __restrict__ h_buf, float* __restrict__ out) {
  __shared__ uint4 w_lds[8192];          // 128 KiB weights (fragment order)
  __shared__ float c_lds[4][16][16];     // gate staging [gate][row][col]

  const int tid  = threadIdx.x;
  const int lane = tid & 63;
  const int wv   = tid >> 6;             // wave 0..3 == gate i,f,g,o
  const int wg   = blockIdx.x;
  const int grp  = wg & 7;               // XCD id under round-robin dispatch
  const int wgj  = wg >> 3;              // 0..31 column slice / weight image
  const int B0   = grp * GB;

  for (int i = tid; i < 8192; i += 256) w_lds[i] = wpack[(size_t)wgj * 8192 + i];

  const int pb   = tid >> 4;             // pointwise row 0..15 (valid < GB)
  const int pc   = tid & 15;             // pointwise col
  const int colg = wgj * 16 + pc;
  const int pbs  = pb & 7;               // safe row for loads (dup for pb>=8)
  float c_reg = c0[(B0 + pbs) * DIM + colg];
  const float bias0 = b_ih[0*512 + colg] + b_hh[0*512 + colg];
  const float bias1 = b_ih[1*512 + colg] + b_hh[1*512 + colg];
  const float bias2 = b_ih[2*512 + colg] + b_hh[2*512 + colg];
  const float bias3 = b_ih[3*512 + colg] + b_hh[3*512 + colg];

  const int m  = lane & 15;              // A-fragment row (rows >=8 duplicate)
  const int m8 = lane & 7;
  const int kq = 8 * (lane >> 4);        // k sub-offset (u16 units)

  const short8* wl = (const short8*)w_lds;
  bool sticky = false;                   // per-wave permanent far-path fallback

  __syncthreads();                       // w_lds ready before ANY wl read

  // publish h0 (parity 0), every word tagged with 1  (write-through)
  {
    float h0f = h0[(B0 + pbs) * DIM + colg];
    float h0n = __shfl_xor(h0f, 1);
    if (pb < GB && !(pc & 1)) {
      uint32_t both = (uint32_t)f2bf(h0f) | ((uint32_t)f2bf(h0n) << 16);
      uint32_t v = (both & ~TAGM) | TAGM;
      uint32_t* p = (uint32_t*)(h_buf + ((size_t)(0 * NGROUP + grp) * GB + pb) * DIM + colg);
      __hip_atomic_store(p, v, __ATOMIC_RELAXED, __HIP_MEMORY_SCOPE_AGENT);
    }
  }

  // x-part of step 0 (overlaps the h0 store flight)
  f32x4 xacc;
  {
    f32x4 a0 = (f32x4){0.f,0.f,0.f,0.f}, a1 = (f32x4){0.f,0.f,0.f,0.f};
    const u16* xrow = xbf + (size_t)(0 * BATCH + B0 + m8) * DIM;
    for (int kt = 0; kt < 16; kt += 2) {
      short8 a = *((const short8*)(xrow + kt * 32 + kq));
      a0 = __builtin_amdgcn_mfma_f32_16x16x32_bf16(a, wl[(wv*32+kt)*64+lane], a0, 0,0,0);
      short8 a2 = *((const short8*)(xrow + (kt+1) * 32 + kq));
      a1 = __builtin_amdgcn_mfma_f32_16x16x32_bf16(a2, wl[(wv*32+kt+1)*64+lane], a1, 0,0,0);
    }
    xacc = a0 + a1;
  }

  for (int t = 0; t < T_STEPS; ++t) {
    const int pr = t & 1;
    const u16* tb = h_buf + (size_t)(pr * NGROUP + grp) * GB * DIM;   // 8 KiB tile
    const uint32_t e = 1u ^ (((uint32_t)t >> 1) & 1u);
    const int esc = (t < 2) ? 256 : 48;

    // ---- merged poll+load: retry tile until every word's tag == e ----
    union HU { u32x4 u; short8 s; } hq[16];
    {
      uint64_t pa2 = (uint64_t)tb + (uint64_t)(m8 * 1024 + (lane >> 4) * 16);
      int spins = 0;
      for (;;) {
#define HLOADS(FLAGS)                                                          \
  do {                                                                         \
    asm volatile("global_load_dwordx4 %0, %1, off offset:0 "   FLAGS : "=v"(hq[0].u)  : "v"(pa2) : "memory"); \
    asm volatile("global_load_dwordx4 %0, %1, off offset:64 "  FLAGS : "=v"(hq[1].u)  : "v"(pa2) : "memory"); \
    asm volatile("global_load_dwordx4 %0, %1, off offset:128 " FLAGS : "=v"(hq[2].u)  : "v"(pa2) : "memory"); \
    asm volatile("global_load_dwordx4 %0, %1, off offset:192 " FLAGS : "=v"(hq[3].u)  : "v"(pa2) : "memory"); \
    asm volatile("global_load_dwordx4 %0, %1, off offset:256 " FLAGS : "=v"(hq[4].u)  : "v"(pa2) : "memory"); \
    asm volatile("global_load_dwordx4 %0, %1, off offset:320 " FLAGS : "=v"(hq[5].u)  : "v"(pa2) : "memory"); \
    asm volatile("global_load_dwordx4 %0, %1, off offset:384 " FLAGS : "=v"(hq[6].u)  : "v"(pa2) : "memory"); \
    asm volatile("global_load_dwordx4 %0, %1, off offset:448 " FLAGS : "=v"(hq[7].u)  : "v"(pa2) : "memory"); \
    asm volatile("global_load_dwordx4 %0, %1, off offset:512 " FLAGS : "=v"(hq[8].u)  : "v"(pa2) : "memory"); \
    asm volatile("global_load_dwordx4 %0, %1, off offset:576 " FLAGS : "=v"(hq[9].u)  : "v"(pa2) : "memory"); \
    asm volatile("global_load_dwordx4 %0, %1, off offset:640 " FLAGS : "=v"(hq[10].u) : "v"(pa2) : "memory"); \
    asm volatile("global_load_dwordx4 %0, %1, off offset:704 " FLAGS : "=v"(hq[11].u) : "v"(pa2) : "memory"); \
    asm volatile("global_load_dwordx4 %0, %1, off offset:768 " FLAGS : "=v"(hq[12].u) : "v"(pa2) : "memory"); \
    asm volatile("global_load_dwordx4 %0, %1, off offset:832 " FLAGS : "=v"(hq[13].u) : "v"(pa2) : "memory"); \
    asm volatile("global_load_dwordx4 %0, %1, off offset:896 " FLAGS : "=v"(hq[14].u) : "v"(pa2) : "memory"); \
    asm volatile("global_load_dwordx4 %0, %1, off offset:960 " FLAGS : "=v"(hq[15].u) : "v"(pa2) : "memory"); \
  } while (0)
        if (!sticky) HLOADS("sc0");        // L2-served fast path (co-XCD)
        else         HLOADS("sc0 sc1");    // far coherent path (always correct)
#undef HLOADS
        asm volatile("s_waitcnt vmcnt(0)" ::: "memory");
        __builtin_amdgcn_sched_barrier(0);
        uint32_t andv = 0xFFFFFFFFu, orv = 0u;
        #pragma unroll
        for (int i = 0; i < 16; ++i) {
          u32x4 v = hq[i].u;
          andv &= v.x & v.y & v.z & v.w;
          orv  |= v.x | v.y | v.z | v.w;
        }
        uint32_t ok = e ? ((andv & TAGM) == TAGM) : ((orv & TAGM) == 0u);
        if (__ballot(ok != 0u) == ~0ull) break;
        if (++spins == esc) sticky = true;       // permanent per-wave escalation
        if (spins > (1 << 16)) break;            // fail loud, never hang
      }
      __builtin_amdgcn_sched_barrier(0);         // keep MFMAs after final waitcnt
    }

    // ---- h-part MFMAs seeded with this step's x-part ----
    f32x4 acc0 = xacc, acc1 = (f32x4){0.f,0.f,0.f,0.f};
    #pragma unroll
    for (int kt = 0; kt < 16; kt += 2) {
      acc0 = __builtin_amdgcn_mfma_f32_16x16x32_bf16(hq[kt].s,   wl[(wv*32+16+kt)*64+lane],   acc0, 0,0,0);
      acc1 = __builtin_amdgcn_mfma_f32_16x16x32_bf16(hq[kt+1].s, wl[(wv*32+16+kt+1)*64+lane], acc1, 0,0,0);
    }
    f32x4 acc = acc0 + acc1;

    // stage C tile: C/D layout col=lane&15, row=(lane>>4)*4+reg (m89-verified)
    {
      int r0 = (lane >> 4) * 4;
      c_lds[wv][r0 + 0][lane & 15] = acc[0];
      c_lds[wv][r0 + 1][lane & 15] = acc[1];
      c_lds[wv][r0 + 2][lane & 15] = acc[2];
      c_lds[wv][r0 + 3][lane & 15] = acc[3];
    }
    __syncthreads();

    // pointwise LSTM cell (rows 0..GB-1 valid -> threads 0..127)
    float gi = fsigmoid(c_lds[0][pbs][pc] + bias0);
    float gf = fsigmoid(c_lds[1][pbs][pc] + bias1);
    float gg = ftanh  (c_lds[2][pbs][pc] + bias2);
    float go = fsigmoid(c_lds[3][pbs][pc] + bias3);
    c_reg = gf * c_reg + gi * gg;
    float h = go * ftanh(c_reg);

    if (t < T_STEPS - 1) {
      // fire tagged h_{t+1} stores into parity pr^1 — write-through, no drain
      {
        float hn = __shfl_xor(h, 1);
        if (pb < GB && !(pc & 1)) {
          uint32_t both = (uint32_t)f2bf(h) | ((uint32_t)f2bf(hn) << 16);
          const uint32_t tagw = 1u ^ ((((uint32_t)t + 1) >> 1) & 1u);
          uint32_t v = (both & ~TAGM) | (tagw * TAGM);
          uint32_t* p = (uint32_t*)(h_buf + ((size_t)((pr ^ 1) * NGROUP + grp) * GB + pb) * DIM + colg);
          __hip_atomic_store(p, v, __ATOMIC_RELAXED, __HIP_MEMORY_SCOPE_AGENT);
        }
      }
      // off-critical-path: output store + next step's x-part (overlaps flight)
      if (pb < GB) out[((size_t)t * BATCH + B0 + pb) * DIM + colg] = h;
      f32x4 a2_0 = (f32x4){0.f,0.f,0.f,0.f}, a2_1 = (f32x4){0.f,0.f,0.f,0.f};
      const u16* xr = xbf + (size_t)((t + 1) * BATCH + B0 + m8) * DIM;
      for (int kt = 0; kt < 16; kt += 2) {
        short8 a = *((const short8*)(xr + kt * 32 + kq));
        a2_0 = __builtin_amdgcn_mfma_f32_16x16x32_bf16(a, wl[(wv*32+kt)*64+lane], a2_0, 0,0,0);
        short8 a2 = *((const short8*)(xr + (kt+1) * 32 + kq));
        a2_1 = __builtin_amdgcn_mfma_f32_16x16x32_bf16(a2, wl[(wv*32+kt+1)*64+lane], a2_1, 0,0,0);
      }
      xacc = a2_0 + a2_1;
    } else if (pb < GB) {
      out[((size_t)t * BATCH + B0 + pb) * DIM + colg] = h;
      out[TBH + (B0 + pb) * DIM + colg]      = h;
      out[TBH + BH + (B0 + pb) * DIM + colg] = c_reg;
    }
  }
}

extern "C" void kernel_launch(void* const* d_in, const int* in_sizes, int n_in,
                              void* d_out, int out_size, void* d_ws, size_t ws_size,
                              hipStream_t stream) {
  (void)in_sizes; (void)n_in; (void)out_size; (void)ws_size;
  const float* x    = (const float*)d_in[0];
  const float* h0   = (const float*)d_in[1];
  const float* c0   = (const float*)d_in[2];
  const float* w_ih = (const float*)d_in[3];
  const float* b_ih = (const float*)d_in[4];
  const float* w_hh = (const float*)d_in[5];
  const float* b_hh = (const float*)d_in[6];
  float* out = (float*)d_out;

  char* ws = (char*)d_ws;
  uint4* wpack = (uint4*)ws;                                    // 4 MiB
  u16*   xbf   = (u16*)(ws + ((size_t)4 << 20));                // 32 MiB
  u16*   hbuf  = (u16*)(ws + ((size_t)36 << 20));               // 128 KiB (2*8*8KiB)

  pack_w_kernel<<<dim3(32),   dim3(256), 0, stream>>>(w_ih, w_hh, wpack);
  pack_x_kernel<<<dim3(8192), dim3(256), 0, stream>>>(x, (uint4*)xbf);

  void* args[] = {(void*)&h0, (void*)&c0, (void*)&b_ih, (void*)&b_hh,
                  (void*)&wpack, (void*)&xbf, (void*)&hbuf, (void*)&out};
  hipError_t e = hipLaunchCooperativeKernel((void*)lstm_persist, dim3(NGROUP * WG_PER_GROUP),
                                            dim3(256), args, 0, stream);
  if (e != hipSuccess) {
    // fallback: 256 blocks @ 1 block/CU on 256 CUs will co-schedule
    lstm_persist<<<dim3(NGROUP * WG_PER_GROUP), dim3(256), 0, stream>>>(
        h0, c0, b_ih, b_hh, wpack, xbf, hbuf, out);
  }
}

// Round 7
// 2756.599 us; speedup vs baseline: 1.0508x; 1.0508x over previous
//
#include <hip/hip_runtime.h>
#include <stdint.h>

#define T_STEPS 512
#define BATCH   64
#define DIM     512            // D == H == 512
#define NGROUP  8              // one group per XCD (blockIdx % 8 round-robin, confirmed r6)
#define WG_PER_GROUP 32
#define GB      8              // batch rows per group
#define TBH     (T_STEPS*BATCH*DIM)
#define BH      (BATCH*DIM)
#define TAGM    0x00010001u

typedef __attribute__((ext_vector_type(8))) short short8;
typedef __attribute__((ext_vector_type(4))) float f32x4;
typedef __attribute__((ext_vector_type(4))) unsigned int u32x4;
typedef unsigned short u16;

__device__ __forceinline__ u16 f2bf(float f) {
  union { float f; uint32_t u; } c; c.f = f;
  uint32_t u = c.u;
  return (u16)((u + 0x7FFFu + ((u >> 16) & 1u)) >> 16);
}

__device__ __forceinline__ float fsigmoid(float x) {
  float e = __expf(-x);
  return __builtin_amdgcn_rcpf(1.f + e);
}
__device__ __forceinline__ float ftanh(float x) {
  float e = __expf(2.f * x);
  return 1.f - 2.f * __builtin_amdgcn_rcpf(e + 1.f);
}

// ---- pack w_ih|w_hh into per-colslice bf16 MFMA B-fragment images -----------
__global__ void pack_w_kernel(const float* __restrict__ w_ih,
                              const float* __restrict__ w_hh,
                              uint4* __restrict__ wpack) {
  int j = blockIdx.x;
  for (int u = threadIdx.x; u < 8192; u += 256) {
    int w    = u >> 11;
    int kt   = (u >> 6) & 31;
    int lane = u & 63;
    int n  = w * 512 + j * 16 + (lane & 15);
    int k0 = kt * 32 + 8 * (lane >> 4);
    const float* src = (k0 < 512) ? (w_ih + (size_t)n * 512 + k0)
                                  : (w_hh + (size_t)n * 512 + (k0 - 512));
    uint32_t p0 = f2bf(src[0]) | ((uint32_t)f2bf(src[1]) << 16);
    uint32_t p1 = f2bf(src[2]) | ((uint32_t)f2bf(src[3]) << 16);
    uint32_t p2 = f2bf(src[4]) | ((uint32_t)f2bf(src[5]) << 16);
    uint32_t p3 = f2bf(src[6]) | ((uint32_t)f2bf(src[7]) << 16);
    wpack[(size_t)j * 8192 + u] = make_uint4(p0, p1, p2, p3);
  }
}

// ---- x (fp32) -> bf16, same [T][B][D] layout --------------------------------
__global__ void pack_x_kernel(const float* __restrict__ x, uint4* __restrict__ xbf) {
  size_t i = (size_t)blockIdx.x * 256 + threadIdx.x;     // unit of 8 elems
  const float4* src = (const float4*)x + i * 2;
  float4 a = src[0], b = src[1];
  uint32_t p0 = f2bf(a.x) | ((uint32_t)f2bf(a.y) << 16);
  uint32_t p1 = f2bf(a.z) | ((uint32_t)f2bf(a.w) << 16);
  uint32_t p2 = f2bf(b.x) | ((uint32_t)f2bf(b.y) << 16);
  uint32_t p3 = f2bf(b.z) | ((uint32_t)f2bf(b.w) << 16);
  xbf[i] = make_uint4(p0, p1, p2, p3);
}

// ---- persistent LSTM --------------------------------------------------------
// Exchange: every bf16 of the h-tile carries a generation tag in its LSB.
// Producer DUAL-stores each word:
//   h_loc: PLAIN store  -> dirty line in own-XCD L2 (co-XCD consumers see it)
//   h_far: sc0 sc1 store -> write-through to LLC (coherent fallback)
// Consumer fast path: sc0 loads (L1-bypass, L2-served) from h_loc; cheap
// staggered 16B/lane probe first, then full tile load + FULL tag validation
// (the authority). After `esc` failed retries the wave escalates PERMANENTLY
// to sc0 sc1 loads from h_far (r5's proven path) — correctness never depends
// on the blockIdx->XCD mapping (G16).
// Tags: write at step t has tag_w = 1^(((t+1)>>1)&1) (h0: 1); reader at step t
// expects e = 1^((t>>1)&1). Per-buffer sequence alternates 1,0,1,0; stale gen
// always mismatches; 0xAA poison (LSB 0) only meets expected-tag-1 reads.
__launch_bounds__(256, 1)
__global__ void lstm_persist(const float* __restrict__ h0, const float* __restrict__ c0,
                             const float* __restrict__ b_ih, const float* __restrict__ b_hh,
                             const uint4* __restrict__ wpack, const u16* __restrict__ xbf,
                             u16* __restrict__ h_loc, u16* __restrict__ h_far,
                             float* __restrict__ out) {
  __shared__ uint4 w_lds[8192];          // 128 KiB weights (fragment order)
  __shared__ float c_lds[4][16][16];     // gate staging [gate][row][col]

  const int tid  = threadIdx.x;
  const int lane = tid & 63;
  const int wv   = tid >> 6;             // wave 0..3 == gate i,f,g,o
  const int wg   = blockIdx.x;
  const int grp  = wg & 7;               // XCD id under round-robin dispatch
  const int wgj  = wg >> 3;              // 0..31 column slice / weight image
  const int B0   = grp * GB;

  for (int i = tid; i < 8192; i += 256) w_lds[i] = wpack[(size_t)wgj * 8192 + i];

  const int pb   = tid >> 4;             // pointwise row (valid < GB)
  const int pc   = tid & 15;             // pointwise col
  const int colg = wgj * 16 + pc;
  const int pbs  = pb & 7;
  float c_reg = c0[(B0 + pbs) * DIM + colg];
  const float bias0 = b_ih[0*512 + colg] + b_hh[0*512 + colg];
  const float bias1 = b_ih[1*512 + colg] + b_hh[1*512 + colg];
  const float bias2 = b_ih[2*512 + colg] + b_hh[2*512 + colg];
  const float bias3 = b_ih[3*512 + colg] + b_hh[3*512 + colg];

  const int m8 = lane & 7;               // A-fragment row (rows >=8 duplicate)
  const int kq = 8 * (lane >> 4);        // k sub-offset (u16 units)

  const short8* wl = (const short8*)w_lds;
  bool sticky = false;                   // per-wave permanent far-path fallback

  // byte offset of this thread's h word within a tile, and probe offset
  const uint64_t stByte = ((uint64_t)pb * DIM + colg) * 2;      // store (pc even)
  const uint64_t prByte = (uint64_t)(lane & 7) * 1024 +          // probe: row l&7,
                          ((uint64_t)(lane >> 3) + (uint64_t)(lane & 7) * 8) * 16; // chunks cover all 32 wgs
  const uint64_t ldByte = (uint64_t)m8 * 1024 + (uint64_t)(lane >> 4) * 16;

  __syncthreads();                       // w_lds ready before ANY wl read

  // publish h0 (parity 0), every word tagged 1, dual store
  {
    float h0f = h0[(B0 + pbs) * DIM + colg];
    float h0n = __shfl_xor(h0f, 1);
    if (pb < GB && !(pc & 1)) {
      uint32_t both = (uint32_t)f2bf(h0f) | ((uint32_t)f2bf(h0n) << 16);
      uint32_t v = (both & ~TAGM) | TAGM;
      uint64_t aL = (uint64_t)(h_loc + (size_t)(0 * NGROUP + grp) * GB * DIM) + stByte;
      uint64_t aF = (uint64_t)(h_far + (size_t)(0 * NGROUP + grp) * GB * DIM) + stByte;
      asm volatile("global_store_dword %0, %1, off"          :: "v"(aL), "v"(v) : "memory");
      asm volatile("global_store_dword %0, %1, off sc0 sc1"  :: "v"(aF), "v"(v) : "memory");
    }
  }

  // x-part of step 0 (overlaps the h0 store flight)
  f32x4 xacc;
  {
    f32x4 a0 = (f32x4){0.f,0.f,0.f,0.f}, a1 = (f32x4){0.f,0.f,0.f,0.f};
    const u16* xrow = xbf + (size_t)(0 * BATCH + B0 + m8) * DIM;
    for (int kt = 0; kt < 16; kt += 2) {
      short8 a = *((const short8*)(xrow + kt * 32 + kq));
      a0 = __builtin_amdgcn_mfma_f32_16x16x32_bf16(a, wl[(wv*32+kt)*64+lane], a0, 0,0,0);
      short8 a2 = *((const short8*)(xrow + (kt+1) * 32 + kq));
      a1 = __builtin_amdgcn_mfma_f32_16x16x32_bf16(a2, wl[(wv*32+kt+1)*64+lane], a1, 0,0,0);
    }
    xacc = a0 + a1;
  }

  for (int t = 0; t < T_STEPS; ++t) {
    const int pr = t & 1;
    const uint64_t tbL = (uint64_t)(h_loc + (size_t)(pr * NGROUP + grp) * GB * DIM);
    const uint64_t tbF = (uint64_t)(h_far + (size_t)(pr * NGROUP + grp) * GB * DIM);
    const uint32_t e = 1u ^ (((uint32_t)t >> 1) & 1u);
    const int esc = (t < 2) ? 256 : 48;

    // ---- poll+load: cheap staggered probe, then full tile + full validation --
    union HU { u32x4 u; short8 s; } hq[16];
    {
      int spins = 0;
      for (;;) {
        const uint64_t tb = sticky ? tbF : tbL;
        // cheap probe: 16B/lane, rows l&7, chunk set spans all 32 wg col-slices
        {
          u32x4 s;
          uint64_t pa = tb + prByte;
          if (!sticky) asm volatile("global_load_dwordx4 %0, %1, off sc0"     : "=v"(s) : "v"(pa) : "memory");
          else         asm volatile("global_load_dwordx4 %0, %1, off sc0 sc1" : "=v"(s) : "v"(pa) : "memory");
          asm volatile("s_waitcnt vmcnt(0)" ::: "memory");
          __builtin_amdgcn_sched_barrier(0);
          uint32_t andv = s.x & s.y & s.z & s.w;
          uint32_t orv  = s.x | s.y | s.z | s.w;
          uint32_t ok = e ? ((andv & TAGM) == TAGM) : ((orv & TAGM) == 0u);
          if (__ballot(ok != 0u) != ~0ull) {
            if (++spins == esc) sticky = true;
            if (spins > (1 << 16)) break;        // fail loud, never hang
            continue;
          }
        }
        // full tile load (authoritative validation)
        {
          uint64_t pa2 = tb + ldByte;
#define HLOADS(FLAGS)                                                          \
  do {                                                                         \
    asm volatile("global_load_dwordx4 %0, %1, off offset:0 "   FLAGS : "=v"(hq[0].u)  : "v"(pa2) : "memory"); \
    asm volatile("global_load_dwordx4 %0, %1, off offset:64 "  FLAGS : "=v"(hq[1].u)  : "v"(pa2) : "memory"); \
    asm volatile("global_load_dwordx4 %0, %1, off offset:128 " FLAGS : "=v"(hq[2].u)  : "v"(pa2) : "memory"); \
    asm volatile("global_load_dwordx4 %0, %1, off offset:192 " FLAGS : "=v"(hq[3].u)  : "v"(pa2) : "memory"); \
    asm volatile("global_load_dwordx4 %0, %1, off offset:256 " FLAGS : "=v"(hq[4].u)  : "v"(pa2) : "memory"); \
    asm volatile("global_load_dwordx4 %0, %1, off offset:320 " FLAGS : "=v"(hq[5].u)  : "v"(pa2) : "memory"); \
    asm volatile("global_load_dwordx4 %0, %1, off offset:384 " FLAGS : "=v"(hq[6].u)  : "v"(pa2) : "memory"); \
    asm volatile("global_load_dwordx4 %0, %1, off offset:448 " FLAGS : "=v"(hq[7].u)  : "v"(pa2) : "memory"); \
    asm volatile("global_load_dwordx4 %0, %1, off offset:512 " FLAGS : "=v"(hq[8].u)  : "v"(pa2) : "memory"); \
    asm volatile("global_load_dwordx4 %0, %1, off offset:576 " FLAGS : "=v"(hq[9].u)  : "v"(pa2) : "memory"); \
    asm volatile("global_load_dwordx4 %0, %1, off offset:640 " FLAGS : "=v"(hq[10].u) : "v"(pa2) : "memory"); \
    asm volatile("global_load_dwordx4 %0, %1, off offset:704 " FLAGS : "=v"(hq[11].u) : "v"(pa2) : "memory"); \
    asm volatile("global_load_dwordx4 %0, %1, off offset:768 " FLAGS : "=v"(hq[12].u) : "v"(pa2) : "memory"); \
    asm volatile("global_load_dwordx4 %0, %1, off offset:832 " FLAGS : "=v"(hq[13].u) : "v"(pa2) : "memory"); \
    asm volatile("global_load_dwordx4 %0, %1, off offset:896 " FLAGS : "=v"(hq[14].u) : "v"(pa2) : "memory"); \
    asm volatile("global_load_dwordx4 %0, %1, off offset:960 " FLAGS : "=v"(hq[15].u) : "v"(pa2) : "memory"); \
  } while (0)
          if (!sticky) HLOADS("sc0");
          else         HLOADS("sc0 sc1");
#undef HLOADS
          asm volatile("s_waitcnt vmcnt(0)" ::: "memory");
          __builtin_amdgcn_sched_barrier(0);
          uint32_t andv = 0xFFFFFFFFu, orv = 0u;
          #pragma unroll
          for (int i = 0; i < 16; ++i) {
            u32x4 v = hq[i].u;
            andv &= v.x & v.y & v.z & v.w;
            orv  |= v.x | v.y | v.z | v.w;
          }
          uint32_t ok = e ? ((andv & TAGM) == TAGM) : ((orv & TAGM) == 0u);
          if (__ballot(ok != 0u) == ~0ull) break;
          if (++spins == esc) sticky = true;
          if (spins > (1 << 16)) break;          // fail loud, never hang
        }
      }
      __builtin_amdgcn_sched_barrier(0);         // keep MFMAs after final waitcnt
    }

    // ---- h-part MFMAs seeded with this step's x-part ----
    f32x4 acc0 = xacc, acc1 = (f32x4){0.f,0.f,0.f,0.f};
    #pragma unroll
    for (int kt = 0; kt < 16; kt += 2) {
      acc0 = __builtin_amdgcn_mfma_f32_16x16x32_bf16(hq[kt].s,   wl[(wv*32+16+kt)*64+lane],   acc0, 0,0,0);
      acc1 = __builtin_amdgcn_mfma_f32_16x16x32_bf16(hq[kt+1].s, wl[(wv*32+16+kt+1)*64+lane], acc1, 0,0,0);
    }
    f32x4 acc = acc0 + acc1;

    // stage C tile: C/D layout col=lane&15, row=(lane>>4)*4+reg (m89-verified)
    {
      int r0 = (lane >> 4) * 4;
      c_lds[wv][r0 + 0][lane & 15] = acc[0];
      c_lds[wv][r0 + 1][lane & 15] = acc[1];
      c_lds[wv][r0 + 2][lane & 15] = acc[2];
      c_lds[wv][r0 + 3][lane & 15] = acc[3];
    }
    __syncthreads();

    // pointwise LSTM cell
    float gi = fsigmoid(c_lds[0][pbs][pc] + bias0);
    float gf = fsigmoid(c_lds[1][pbs][pc] + bias1);
    float gg = ftanh  (c_lds[2][pbs][pc] + bias2);
    float go = fsigmoid(c_lds[3][pbs][pc] + bias3);
    c_reg = gf * c_reg + gi * gg;
    float h = go * ftanh(c_reg);

    if (t < T_STEPS - 1) {
      // dual tagged h_{t+1} stores into parity pr^1 — fire and forget
      {
        float hn = __shfl_xor(h, 1);
        if (pb < GB && !(pc & 1)) {
          uint32_t both = (uint32_t)f2bf(h) | ((uint32_t)f2bf(hn) << 16);
          const uint32_t tagw = 1u ^ ((((uint32_t)t + 1) >> 1) & 1u);
          uint32_t v = (both & ~TAGM) | (tagw * TAGM);
          uint64_t aL = (uint64_t)(h_loc + (size_t)((pr ^ 1) * NGROUP + grp) * GB * DIM) + stByte;
          uint64_t aF = (uint64_t)(h_far + (size_t)((pr ^ 1) * NGROUP + grp) * GB * DIM) + stByte;
          asm volatile("global_store_dword %0, %1, off"         :: "v"(aL), "v"(v) : "memory");
          asm volatile("global_store_dword %0, %1, off sc0 sc1" :: "v"(aF), "v"(v) : "memory");
        }
      }
      // off-critical-path: output store + next step's x-part (overlaps flight)
      if (pb < GB) out[((size_t)t * BATCH + B0 + pb) * DIM + colg] = h;
      f32x4 a2_0 = (f32x4){0.f,0.f,0.f,0.f}, a2_1 = (f32x4){0.f,0.f,0.f,0.f};
      const u16* xr = xbf + (size_t)((t + 1) * BATCH + B0 + m8) * DIM;
      for (int kt = 0; kt < 16; kt += 2) {
        short8 a = *((const short8*)(xr + kt * 32 + kq));
        a2_0 = __builtin_amdgcn_mfma_f32_16x16x32_bf16(a, wl[(wv*32+kt)*64+lane], a2_0, 0,0,0);
        short8 a2 = *((const short8*)(xr + (kt+1) * 32 + kq));
        a2_1 = __builtin_amdgcn_mfma_f32_16x16x32_bf16(a2, wl[(wv*32+kt+1)*64+lane], a2_1, 0,0,0);
      }
      xacc = a2_0 + a2_1;
    } else if (pb < GB) {
      out[((size_t)t * BATCH + B0 + pb) * DIM + colg] = h;
      out[TBH + (B0 + pb) * DIM + colg]      = h;
      out[TBH + BH + (B0 + pb) * DIM + colg] = c_reg;
    }
  }
}

extern "C" void kernel_launch(void* const* d_in, const int* in_sizes, int n_in,
                              void* d_out, int out_size, void* d_ws, size_t ws_size,
                              hipStream_t stream) {
  (void)in_sizes; (void)n_in; (void)out_size; (void)ws_size;
  const float* x    = (const float*)d_in[0];
  const float* h0   = (const float*)d_in[1];
  const float* c0   = (const float*)d_in[2];
  const float* w_ih = (const float*)d_in[3];
  const float* b_ih = (const float*)d_in[4];
  const float* w_hh = (const float*)d_in[5];
  const float* b_hh = (const float*)d_in[6];
  float* out = (float*)d_out;

  char* ws = (char*)d_ws;
  uint4* wpack = (uint4*)ws;                                    // 4 MiB
  u16*   xbf   = (u16*)(ws + ((size_t)4 << 20));                // 32 MiB
  u16*   hloc  = (u16*)(ws + ((size_t)36 << 20));               // 128 KiB
  u16*   hfar  = (u16*)(ws + ((size_t)37 << 20));               // 128 KiB

  pack_w_kernel<<<dim3(32),   dim3(256), 0, stream>>>(w_ih, w_hh, wpack);
  pack_x_kernel<<<dim3(8192), dim3(256), 0, stream>>>(x, (uint4*)xbf);

  void* args[] = {(void*)&h0, (void*)&c0, (void*)&b_ih, (void*)&b_hh,
                  (void*)&wpack, (void*)&xbf, (void*)&hloc, (void*)&hfar, (void*)&out};
  hipError_t e = hipLaunchCooperativeKernel((void*)lstm_persist, dim3(NGROUP * WG_PER_GROUP),
                                            dim3(256), args, 0, stream);
  if (e != hipSuccess) {
    lstm_persist<<<dim3(NGROUP * WG_PER_GROUP), dim3(256), 0, stream>>>(
        h0, c0, b_ih, b_hh, wpack, xbf, hloc, hfar, out);
  }
}